// Round 20
// baseline (419.924 us; speedup 1.0000x reference)
//
#include <hip/hip_runtime.h>
#include <hip/hip_bf16.h>

// ---- problem constants (match reference) ----
#define NP 100000
#define NA 50000
#define NTOT 150000          // NP+NA
#define E0 300000
#define E1 300000
#define E2 200000
#define ETOT 800000
#define NH 4
#define HD 16
#define HID 64
#define IN_DIM 128
#define KQV 192
#define LAYERS 2
#define NSRC 250000          // NA + 2*NP
#define JP 320               // fused paper cols: q | k_et1 | k_et2 | v_et1 | v_et2
#define JA 192               // fused author cols: q | k_et0 | v_et0
#define NCH 586              // ceil(NTOT/256)
#define PT 1563              // ceil(NP/64)
#define AT 782               // ceil(NA/64)
#define LSPAN 33280          // per-layer fuse_weights idx span = 65*(JP+JA)

typedef __attribute__((ext_vector_type(8))) short bf16x8;   // 8 bf16 (4 VGPRs)
typedef __attribute__((ext_vector_type(4))) float f32x4;    // MFMA C/D
typedef _Float16 h16x2 __attribute__((ext_vector_type(2)));

__device__ __forceinline__ float gelu_exact(float x) {
    return 0.5f * x * (1.0f + erff(x * 0.7071067811865475f));
}
__device__ __forceinline__ unsigned short f2bf(float f) {
    unsigned u = __float_as_uint(f);
    return (unsigned short)((u + 0x7fffu + ((u >> 16) & 1u)) >> 16);
}
__device__ __forceinline__ float bf2f(unsigned short b) {
    return __uint_as_float((unsigned)b << 16);
}
__device__ __forceinline__ unsigned short f2h(float f) {
    union { _Float16 h; unsigned short u; } c;
    c.h = (_Float16)f;
    return c.u;
}

__device__ __forceinline__ void edge_decode(int e, const int* __restrict__ ei_ap,
                                            const int* __restrict__ ei_pa,
                                            const int* __restrict__ ei_pp,
                                            int& src, int& dst) {
    if (e < E0)            { src = ei_ap[e];                 dst = ei_ap[E0 + e]; }
    else if (e < E0 + E1)  { int le = e - E0;
                             src = NA + ei_pa[le];           dst = NP + ei_pa[E1 + le]; }
    else                   { int le = e - E0 - E1;
                             src = NA + NP + ei_pp[le];      dst = ei_pp[E2 + le]; }
}

// ---------------- CSR build ----------------
__global__ void csr_count_kernel(const int* __restrict__ ei_ap, const int* __restrict__ ei_pa,
                                 const int* __restrict__ ei_pp, int* __restrict__ cnt) {
    int e = blockIdx.x * 256 + threadIdx.x;
    if (e >= ETOT) return;
    int src, dst; edge_decode(e, ei_ap, ei_pa, ei_pp, src, dst);
    atomicAdd(&cnt[dst], 1);
}

__global__ void scan_chunk_sums(const int* __restrict__ cnt, int* __restrict__ csum) {
    __shared__ int sd[256];
    int c = blockIdx.x, t = threadIdx.x;
    int i = c * 256 + t;
    sd[t] = (i < NTOT) ? cnt[i] : 0;
    __syncthreads();
    for (int o = 128; o > 0; o >>= 1) { if (t < o) sd[t] += sd[t + o]; __syncthreads(); }
    if (t == 0) csum[c] = sd[0];
}

__global__ void scan_offsets(const int* __restrict__ csum, int* __restrict__ coff, int nch) {
    __shared__ int sd[1024];
    int t = threadIdx.x;
    int v = (t < nch) ? csum[t] : 0;
    sd[t] = v;
    __syncthreads();
    for (int o = 1; o < 1024; o <<= 1) {
        int x = (t >= o) ? sd[t - o] : 0;
        __syncthreads();
        sd[t] += x;
        __syncthreads();
    }
    if (t < nch) coff[t] = sd[t] - v;   // exclusive
}

__global__ void scan_final(const int* __restrict__ cnt, const int* __restrict__ coff,
                           int* __restrict__ row_ptr, int* __restrict__ cursor) {
    __shared__ int sd[256];
    int c = blockIdx.x, t = threadIdx.x, i = c * 256 + t;
    int v = (i < NTOT) ? cnt[i] : 0;
    sd[t] = v;
    __syncthreads();
    for (int o = 1; o < 256; o <<= 1) {
        int x = (t >= o) ? sd[t - o] : 0;
        __syncthreads();
        sd[t] += x;
        __syncthreads();
    }
    if (i < NTOT) { int ex = coff[c] + sd[t] - v; row_ptr[i] = ex; cursor[i] = ex; }
    if (i == 0) row_ptr[NTOT] = ETOT;
}

__global__ void csr_fill_kernel(const int* __restrict__ ei_ap, const int* __restrict__ ei_pa,
                                const int* __restrict__ ei_pp, int* __restrict__ cursor,
                                int* __restrict__ edge_src) {
    int e = blockIdx.x * 256 + threadIdx.x;
    if (e >= ETOT) return;
    int src, dst; edge_decode(e, ei_ap, ei_pa, ei_pp, src, dst);
    int pos = atomicAdd(&cursor[dst], 1);
    edge_src[pos] = src;
}

// ---------------- one-time weight prep: transposed bf16 panels ----------------
__global__ void prep_weights(const float* __restrict__ W_in, const float* __restrict__ W_hout,
                             const float* __restrict__ W_out,
                             unsigned short* __restrict__ WinT,
                             unsigned short* __restrict__ WhoutT,
                             unsigned short* __restrict__ WoutT) {
    int idx = blockIdx.x * 256 + threadIdx.x;
    if (idx < 2 * 64 * IN_DIM) {
        int t = idx >> 13, r = idx & 8191;
        int c = r >> 7, k = r & 127;
        WinT[idx] = f2bf(W_in[(size_t)t * IN_DIM * HID + (size_t)k * HID + c]);
        return;
    }
    int i2 = idx - 2 * 64 * IN_DIM;
    if (i2 < LAYERS * 2 * 4096) {
        int p = i2 >> 12, r = i2 & 4095;
        int c = r >> 6, k = r & 63;
        WhoutT[i2] = f2bf(W_hout[(size_t)p * 4096 + (size_t)k * HID + c]);
        return;
    }
    int i3 = i2 - LAYERS * 2 * 4096;
    if (i3 < 2 * 4096) {
        int p = i3 >> 12, r = i3 & 4095;
        int c = r >> 6, k = r & 63;
        WoutT[i3] = f2bf(W_out[(size_t)p * 4096 + (size_t)k * HID + c]);
    }
}

// ---------------- fused-weight build, BOTH layers in one launch ----------------
__global__ void fuse_weights_all(const float* __restrict__ Wkqv, const float* __restrict__ bkqv,
                                 const float* __restrict__ Wkrel, const float* __restrict__ Wvrel,
                                 unsigned short* __restrict__ WfpT, float* __restrict__ bfp,
                                 unsigned short* __restrict__ WfaT, float* __restrict__ bfa) {
    int gidx = blockIdx.x * 256 + threadIdx.x;
    if (gidx >= LAYERS * LSPAN) return;
    int lay = gidx / LSPAN;
    int idx = gidx - lay * LSPAN;
    const float* Wkqv_l = Wkqv + (size_t)lay * 2 * HID * KQV;
    const float* bkqv_l = bkqv + (size_t)lay * 2 * KQV;
    const float* Wkrel_l = Wkrel + (size_t)lay * 3 * NH * HD * HD;
    const float* Wvrel_l = Wvrel + (size_t)lay * 3 * NH * HD * HD;
    unsigned short* WfpT_l = WfpT + (size_t)lay * JP * 64;
    unsigned short* WfaT_l = WfaT + (size_t)lay * JA * 64;
    float* bfp_l = bfp + (size_t)lay * JP;
    float* bfa_l = bfa + (size_t)lay * JA;

    int type, i, j;
    if (idx < 65 * JP) { type = 0; i = idx / JP; j = idx % JP; }
    else {
        int r = idx - 65 * JP;
        type = 1; i = r / JA; j = r % JA;
    }
    int c = j >> 6, jj = j & 63, h = jj >> 4, e = jj & 15;
    const float* Wk = Wkqv_l + (size_t)type * HID * KQV;
    const float* bk = bkqv_l + type * KQV;
    float val;
    if (c == 0) {
        val = (i < 64) ? Wk[i * KQV + 64 + jj] : bk[64 + jj];
    } else {
        int et, isV;
        if (type == 0) { et = (c == 1 || c == 3) ? 1 : 2; isV = (c >= 3); }
        else           { et = 0; isV = (c == 2); }
        const float* Wr = (isV ? Wvrel_l : Wkrel_l) + (size_t)(et * NH + h) * HD * HD;
        int sb = (isV ? 128 : 0) + h * HD;
        val = 0.0f;
        #pragma unroll
        for (int d = 0; d < HD; d++) {
            float a = (i < 64) ? Wk[i * KQV + sb + d] : bk[sb + d];
            val += a * Wr[d * HD + e];
        }
    }
    if (i < 64) (type ? WfaT_l : WfpT_l)[(size_t)j * 64 + i] = f2bf(val);
    else        (type ? bfa_l : bfp_l)[j] = val;
}

// ---------------- r16-strip MFMA with B loaded straight from GLOBAL ----------------
// Wave owns rows [w16, w16+16); B-frag = Wg[(f*16+lrow)*64 + ks*32 + lgrp*8] (16B, L2-hot).
__device__ __forceinline__ void mfma_r16g(const unsigned short* __restrict__ X,
                                          const unsigned short* __restrict__ Wg,
                                          int w16, int lrow, int lgrp, f32x4* acc) {
    bf16x8 bfr[4][2];
    #pragma unroll
    for (int f = 0; f < 4; f++)
        #pragma unroll
        for (int ks = 0; ks < 2; ks++)
            bfr[f][ks] = *(const bf16x8*)(Wg + (size_t)(f * 16 + lrow) * 64 + ks * 32 + lgrp * 8);
    #pragma unroll
    for (int f = 0; f < 4; f++) acc[f] = (f32x4){0.f, 0.f, 0.f, 0.f};
    #pragma unroll
    for (int ks = 0; ks < 2; ks++) {
        bf16x8 a = *(const bf16x8*)&X[(w16 + lrow) * 72 + ks * 32 + lgrp * 8];
        #pragma unroll
        for (int f = 0; f < 4; f++)
            acc[f] = __builtin_amdgcn_mfma_f32_16x16x32_bf16(a, bfr[f][ks], acc[f], 0, 0, 0);
    }
}

// K=128 variant (input projection): X stride 136, Wg stride 128
__device__ __forceinline__ void mfma_r16g_k128(const unsigned short* __restrict__ X,
                                               const unsigned short* __restrict__ Wg,
                                               int w16, int lrow, int lgrp, f32x4* acc) {
    #pragma unroll
    for (int f = 0; f < 4; f++) acc[f] = (f32x4){0.f, 0.f, 0.f, 0.f};
    #pragma unroll
    for (int ks = 0; ks < 4; ks++) {
        bf16x8 a = *(const bf16x8*)&X[(w16 + lrow) * 136 + ks * 32 + lgrp * 8];
        #pragma unroll
        for (int f = 0; f < 4; f++) {
            bf16x8 bb = *(const bf16x8*)(Wg + (size_t)(f * 16 + lrow) * 128 + ks * 32 + lgrp * 8);
            acc[f] = __builtin_amdgcn_mfma_f32_16x16x32_bf16(a, bb, acc[f], 0, 0, 0);
        }
    }
}

__device__ __forceinline__ void store_q4(const f32x4* q, const float* bias,
                                         int lrow, int lgrp, int w16, int nb, int N,
                                         bool even, unsigned short* Qbase) {
    #pragma unroll
    for (int fp = 0; fp < 4; fp += 2) {
        int c0 = fp * 16 + lrow, c1 = c0 + 16;
        float b0 = bias[c0], b1 = bias[c1];
        #pragma unroll
        for (int r = 0; r < 4; r++) {
            int n = nb + w16 + lgrp * 4 + r;
            unsigned own = (unsigned)f2h(q[fp][r] + b0) | ((unsigned)f2h(q[fp + 1][r] + b1) << 16);
            unsigned oth = __shfl_xor(own, 1, 64);
            if (even && n < N) {
                unsigned* qp = (unsigned*)(Qbase + (size_t)n * HID);
                qp[c0 >> 1] = (own & 0xffffu) | (oth << 16);
                qp[c1 >> 1] = (own >> 16) | (oth & 0xffff0000u);
            }
        }
    }
}

__device__ __forceinline__ void store_kv4(const f32x4* kk, const f32x4* vv,
                                          const float* bias, int kc, int vc,
                                          int lrow, int lgrp, int w16, int nb, int N,
                                          bool even, int noff, unsigned* KVb) {
    #pragma unroll
    for (int fp = 0; fp < 4; fp += 2) {
        int c0 = fp * 16 + lrow, c1 = c0 + 16;
        float bk0 = bias[kc + c0], bk1 = bias[kc + c1];
        float bv0 = bias[vc + c0], bv1 = bias[vc + c1];
        #pragma unroll
        for (int r = 0; r < 4; r++) {
            int n = nb + w16 + lgrp * 4 + r;
            unsigned own0 = (unsigned)f2h(kk[fp][r] + bk0) | ((unsigned)f2h(vv[fp][r] + bv0) << 16);
            unsigned oth0 = __shfl_xor(own0, 1, 64);
            unsigned own1 = (unsigned)f2h(kk[fp + 1][r] + bk1) | ((unsigned)f2h(vv[fp + 1][r] + bv1) << 16);
            unsigned oth1 = __shfl_xor(own1, 1, 64);
            if (n < N) {
                unsigned* dst = KVb + (((size_t)(noff + n)) << 6);
                unsigned w0 = even ? ((own0 & 0xffffu) | (oth0 << 16))
                                   : ((oth0 >> 16) | (own0 & 0xffff0000u));
                unsigned w1 = even ? ((own1 & 0xffffu) | (oth1 << 16))
                                   : ((oth1 >> 16) | (own1 & 0xffff0000u));
                dst[c0] = w0;
                dst[c1] = w1;
            }
        }
    }
}

// Q/K/V tail over the wave's own 16 rows (XS stride 72); all B from global, no barriers.
__device__ __forceinline__ void kqv_tail_g(const unsigned short* __restrict__ XS,
                                           const unsigned short* __restrict__ WT2,
                                           const float* __restrict__ bias2,
                                           int type, int nb, int N,
                                           int w16, int lrow, int lgrp, bool even,
                                           unsigned short* __restrict__ Qh,
                                           unsigned* __restrict__ KVb) {
    f32x4 q[4];
    mfma_r16g(XS, WT2, w16, lrow, lgrp, q);
    store_q4(q, bias2, lrow, lgrp, w16, nb, N, even, Qh + (size_t)(type ? NP : 0) * HID);
    int kc1 = 64, vc1 = type ? 128 : 192;
    int nf1 = type ? 0 : NA;
    f32x4 kk[4], vv[4];
    mfma_r16g(XS, WT2 + (size_t)kc1 * 64, w16, lrow, lgrp, kk);
    mfma_r16g(XS, WT2 + (size_t)vc1 * 64, w16, lrow, lgrp, vv);
    store_kv4(kk, vv, bias2, kc1, vc1, lrow, lgrp, w16, nb, N, even, nf1, KVb);
    if (type == 0) {
        mfma_r16g(XS, WT2 + (size_t)128 * 64, w16, lrow, lgrp, kk);
        mfma_r16g(XS, WT2 + (size_t)256 * 64, w16, lrow, lgrp, vv);
        store_kv4(kk, vv, bias2, 128, 256, lrow, lgrp, w16, nb, N, even, NA + NP, KVb);
    }
}

// ---------------- gemm_in fused with layer-0 kqv (r16 strips, global-B) ----------------
__global__ __launch_bounds__(256) void gemm_in_kqv(
    const float* __restrict__ xp, const float* __restrict__ xa,
    const unsigned short* __restrict__ WinT, const float* __restrict__ b_in,
    const unsigned short* __restrict__ WfpT, const float* __restrict__ bfp,
    const unsigned short* __restrict__ WfaT, const float* __restrict__ bfa,
    unsigned short* __restrict__ Hb, unsigned short* __restrict__ Qh,
    unsigned* __restrict__ KVb)
{
    __shared__ unsigned short XB[64 * 136];   // 17408 B
    __shared__ unsigned short HS[64 * 72];    //  9216 B

    int b = blockIdx.x, tid = threadIdx.x;
    int type = (b >= PT);
    int tile = type ? (b - PT) : b;
    int N = type ? NA : NP;
    const float* X = type ? xa : xp;
    const unsigned short* WT = WinT + (size_t)type * 64 * IN_DIM;
    const float* bias = b_in + type * HID;
    unsigned short* H = Hb + (type ? (size_t)NP * HID : 0);
    int nb = tile * 64;

    int w = tid >> 6, lane = tid & 63;
    int w16 = w * 16, lrow = lane & 15, lgrp = lane >> 4;
    bool even = ((lrow & 1) == 0);

    // stage own 16 rows of x as bf16 (wave-local)
    {
        int row = w16 + (lane >> 2), cg = (lane & 3) * 32;
        int n = nb + row;
        if (n < N) {
            const float* xr = X + (size_t)n * IN_DIM + cg;
            #pragma unroll
            for (int i = 0; i < 32; i += 4) {
                float4 v = *(const float4*)(xr + i);
                *(ushort4*)&XB[row * 136 + cg + i] =
                    make_ushort4(f2bf(v.x), f2bf(v.y), f2bf(v.z), f2bf(v.w));
            }
        } else {
            #pragma unroll
            for (int i = 0; i < 32; i += 4)
                *(ushort4*)&XB[row * 136 + cg + i] = make_ushort4(0, 0, 0, 0);
        }
    }
    __syncthreads();

    f32x4 acc[4];
    mfma_r16g_k128(XB, WT, w16, lrow, lgrp, acc);

    // h = acc + bias: write Hb packed + fill HS own rows
    float bh[4];
    #pragma unroll
    for (int f = 0; f < 4; f++) bh[f] = bias[f * 16 + lrow];
    #pragma unroll
    for (int r = 0; r < 4; r++) {
        int n = nb + w16 + lgrp * 4 + r;
        float hv[4];
        #pragma unroll
        for (int f = 0; f < 4; f++) {
            hv[f] = acc[f][r] + bh[f];
            HS[(w16 + lgrp * 4 + r) * 72 + f * 16 + lrow] = f2bf(hv[f]);
        }
        #pragma unroll
        for (int fp = 0; fp < 4; fp += 2) {
            int c0 = fp * 16 + lrow, c1 = c0 + 16;
            unsigned own = (unsigned)f2bf(hv[fp]) | ((unsigned)f2bf(hv[fp + 1]) << 16);
            unsigned oth = __shfl_xor(own, 1, 64);
            if (even && n < N) {
                unsigned* hp = (unsigned*)(H + (size_t)n * HID);
                hp[c0 >> 1] = (own & 0xffffu) | (oth << 16);
                hp[c1 >> 1] = (own >> 16) | (oth & 0xffff0000u);
            }
        }
    }
    __syncthreads();

    const unsigned short* WT2 = type ? WfaT : WfpT;
    const float* bias2 = type ? bfa : bfp;
    kqv_tail_g(HS, WT2, bias2, type, nb, N, w16, lrow, lgrp, even, Qh, KVb);
}

// ---------------- fused attention (unchanged) ----------------
__global__ __launch_bounds__(256) void attn_kernel(
    const unsigned short* __restrict__ Qh, const unsigned* __restrict__ KVb,
    const float* __restrict__ p_rel, const int* __restrict__ row_ptr,
    const int* __restrict__ edge_src, unsigned short* __restrict__ ABf)
{
    int wid = threadIdx.x >> 6, lane = threadIdx.x & 63;
    int n = blockIdx.x * 4 + wid;
    if (n >= NTOT) return;
    int half = lane >> 5;
    int p = lane & 31;
    int h = p >> 3;
    unsigned qw = *(const unsigned*)(Qh + (((size_t)n) << 6) + 2 * p);
    union { unsigned u; h16x2 v; _Float16 f[2]; } qc; qc.u = qw;
    h16x2 qh = qc.v;
    const float INV_LN2 = 1.4426950408889634f;
    float pr0 = p_rel[h] * 0.25f * INV_LN2;
    float pr1 = p_rel[4 + h] * 0.25f * INV_LN2;
    float pr2 = p_rel[8 + h] * 0.25f * INV_LN2;
    int beg = row_ptr[n], end = row_ptr[n + 1];
    float s = 0.0f, acc0 = 0.f, acc1 = 0.f;
    for (int e = beg; e < end; e += 4) {
        int e0 = e + half;
        int e1 = e + 2 + half;
        bool v0 = (e0 < end), v1 = (e1 < end);
        int s0 = v0 ? edge_src[e0] : 0;
        int s1 = v1 ? edge_src[e1] : 0;
        uint2 kv0 = *(const uint2*)(KVb + (((size_t)s0) << 6) + 2 * p);
        uint2 kv1 = *(const uint2*)(KVb + (((size_t)s1) << 6) + 2 * p);
        float d0, d1;
#if __has_builtin(__builtin_amdgcn_fdot2)
        {
            union { unsigned u; h16x2 v; } ck;
            ck.u = kv0.x; d0 = __builtin_amdgcn_fdot2(qh, ck.v, 0.0f, false);
            ck.u = kv1.x; d1 = __builtin_amdgcn_fdot2(qh, ck.v, 0.0f, false);
        }
#else
        {
            union { unsigned u; _Float16 f[2]; } ck;
            float q0 = (float)qc.f[0], q1 = (float)qc.f[1];
            ck.u = kv0.x; d0 = q0 * (float)ck.f[0] + q1 * (float)ck.f[1];
            ck.u = kv1.x; d1 = q0 * (float)ck.f[0] + q1 * (float)ck.f[1];
        }
#endif
        d0 += __shfl_xor(d0, 1, 64);  d1 += __shfl_xor(d1, 1, 64);
        d0 += __shfl_xor(d0, 2, 64);  d1 += __shfl_xor(d1, 2, 64);
        d0 += __shfl_xor(d0, 4, 64);  d1 += __shfl_xor(d1, 4, 64);
        float pa = (s0 < NA) ? pr0 : ((s0 < NA + NP) ? pr1 : pr2);
        float pb = (s1 < NA) ? pr0 : ((s1 < NA + NP) ? pr1 : pr2);
        float a0 = v0 ? fminf(d0 * pa, 80.0f) : -INFINITY;
        float a1 = v1 ? fminf(d1 * pb, 80.0f) : -INFINITY;
        float p0 = exp2f(a0);
        float p1 = exp2f(a1);
        s += p0 + p1;
        union { unsigned u; _Float16 f[2]; } cv0, cv1;
        cv0.u = kv0.y; cv1.u = kv1.y;
        acc0 += p0 * (float)cv0.f[0] + p1 * (float)cv1.f[0];
        acc1 += p0 * (float)cv0.f[1] + p1 * (float)cv1.f[1];
    }
    s    += __shfl_xor(s, 32, 64);
    acc0 += __shfl_xor(acc0, 32, 64);
    acc1 += __shfl_xor(acc1, 32, 64);
    if (half == 0) {
        float inv = 1.0f / (s + 1e-16f);
        unsigned pack = (unsigned)f2bf(acc0 * inv) | ((unsigned)f2bf(acc1 * inv) << 16);
        *(unsigned*)(ABf + (((size_t)n) << 6) + 2 * p) = pack;
    }
}

// ---------------- hout (+ next-layer kqv OR fused W_out), r16 strips, global-B ----------------
// LDS = X tile only (9216B). Each wave stages/restages ITS OWN 16 rows; panels are
// global->register (L2-hot). 2 barriers total (R19: ~16 -> serialization-bound).
__global__ __launch_bounds__(256) void gemm_hout_fused(
    const unsigned short* __restrict__ ABf, const unsigned short* __restrict__ WhT,
    const float* __restrict__ bhout, const float* __restrict__ skip_p,
    const float* __restrict__ lng, const float* __restrict__ lnb,
    unsigned short* __restrict__ Hb,
    const unsigned short* __restrict__ WfpT, const float* __restrict__ bfp,
    const unsigned short* __restrict__ WfaT, const float* __restrict__ bfa,
    unsigned short* __restrict__ Qh, unsigned* __restrict__ KVb,
    const unsigned short* __restrict__ WoT, const float* __restrict__ bout,
    float* __restrict__ outp)
{
    __shared__ unsigned short XbS[64 * 72];   // 9216 B

    int b = blockIdx.x, tid = threadIdx.x;
    int type = (b >= PT);
    int tile = type ? (b - PT) : b;
    int N = type ? NA : NP;
    size_t base_off = type ? (size_t)NP * HID : 0;
    const unsigned short* X = ABf + base_off;
    const unsigned short* W = WhT + (size_t)type * 4096;
    const float* bias = bhout + type * HID;
    unsigned short* H = Hb + base_off;
    int nb = tile * 64;
    bool fin = (WoT != nullptr);

    int w = tid >> 6, lane = tid & 63;
    int w16 = w * 16, lrow = lane & 15, lgrp = lane >> 4;
    bool even = ((lrow & 1) == 0);

    // stage own 16 rows: XbS = gelu(attn_out) bf16
    {
        int row = w16 + (lane >> 2), cg = (lane & 3) * 16;
        int n = nb + row;
        unsigned short tmp[16];
        if (n < N) {
            const unsigned short* xr = X + (((size_t)n) << 6) + cg;
            #pragma unroll
            for (int i = 0; i < 16; i += 4) {
                ushort4 v = *(const ushort4*)(xr + i);
                tmp[i]   = f2bf(gelu_exact(bf2f(v.x)));
                tmp[i+1] = f2bf(gelu_exact(bf2f(v.y)));
                tmp[i+2] = f2bf(gelu_exact(bf2f(v.z)));
                tmp[i+3] = f2bf(gelu_exact(bf2f(v.w)));
            }
        } else {
            #pragma unroll
            for (int i = 0; i < 16; i++) tmp[i] = 0;
        }
        #pragma unroll
        for (int i = 0; i < 16; i += 4)
            *(ushort4*)&XbS[row * 72 + cg + i] =
                make_ushort4(tmp[i], tmp[i+1], tmp[i+2], tmp[i+3]);
    }
    __syncthreads();

    // hout MFMA (B from global)
    f32x4 acc[4];
    mfma_r16g(XbS, W, w16, lrow, lgrp, acc);

    // blend + LN + gelu in registers; write Hb residual (next layer) if !fin
    float a = 1.0f / (1.0f + __expf(-skip_p[type]));
    float oma = 1.0f - a;
    float lnv[4][4];
    {
        float bh[4], gg[4], ll[4];
        #pragma unroll
        for (int f = 0; f < 4; f++) {
            int c = f * 16 + lrow;
            bh[f] = bias[c];
            gg[f] = lng[type * HID + c];
            ll[f] = lnb[type * HID + c];
        }
        #pragma unroll
        for (int r = 0; r < 4; r++) {
            int n = nb + w16 + lgrp * 4 + r;
            float x0, x1, x2, x3;
            if (n < N) {
                const unsigned short* hp = H + (size_t)n * HID;
                x0 = a * (acc[0][r] + bh[0]) + oma * bf2f(hp[0 * 16 + lrow]);
                x1 = a * (acc[1][r] + bh[1]) + oma * bf2f(hp[1 * 16 + lrow]);
                x2 = a * (acc[2][r] + bh[2]) + oma * bf2f(hp[2 * 16 + lrow]);
                x3 = a * (acc[3][r] + bh[3]) + oma * bf2f(hp[3 * 16 + lrow]);
            } else { x0 = x1 = x2 = x3 = 0.f; }
            float sum = x0 + x1 + x2 + x3;
            sum += __shfl_xor(sum, 1, 64); sum += __shfl_xor(sum, 2, 64);
            sum += __shfl_xor(sum, 4, 64); sum += __shfl_xor(sum, 8, 64);
            float mean = sum * (1.0f / 64.0f);
            float d0 = x0 - mean, d1 = x1 - mean, d2 = x2 - mean, d3 = x3 - mean;
            float sq = d0*d0 + d1*d1 + d2*d2 + d3*d3;
            sq += __shfl_xor(sq, 1, 64); sq += __shfl_xor(sq, 2, 64);
            sq += __shfl_xor(sq, 4, 64); sq += __shfl_xor(sq, 8, 64);
            float rstd = rsqrtf(sq * (1.0f / 64.0f) + 1e-5f);
            lnv[r][0] = gelu_exact(d0 * rstd * gg[0] + ll[0]);
            lnv[r][1] = gelu_exact(d1 * rstd * gg[1] + ll[1]);
            lnv[r][2] = gelu_exact(d2 * rstd * gg[2] + ll[2]);
            lnv[r][3] = gelu_exact(d3 * rstd * gg[3] + ll[3]);
            if (!fin) {
                #pragma unroll
                for (int fp = 0; fp < 4; fp += 2) {
                    int c0 = fp * 16 + lrow, c1 = c0 + 16;
                    unsigned own = (unsigned)f2bf(lnv[r][fp]) | ((unsigned)f2bf(lnv[r][fp + 1]) << 16);
                    unsigned oth = __shfl_xor(own, 1, 64);
                    if (even && n < N) {
                        unsigned* hp2 = (unsigned*)(H + (size_t)n * HID);
                        hp2[c0 >> 1] = (own & 0xffffu) | (oth << 16);
                        hp2[c1 >> 1] = (own >> 16) | (oth & 0xffff0000u);
                    }
                }
            }
        }
    }

    // restage own rows: XbS <- bf16(lnv)  (wave-local; data-dep keeps order)
    #pragma unroll
    for (int r = 0; r < 4; r++) {
        int row = w16 + lgrp * 4 + r;
        #pragma unroll
        for (int f = 0; f < 4; f++)
            XbS[row * 72 + f * 16 + lrow] = f2bf(lnv[r][f]);
    }
    __syncthreads();

    if (fin) {
        f32x4 o[4];
        mfma_r16g(XbS, WoT + (size_t)type * 4096, w16, lrow, lgrp, o);
        const float* b2 = bout + type * HID;
        float* O = outp + base_off;
        #pragma unroll
        for (int f = 0; f < 4; f++) {
            int c = f * 16 + lrow;
            float bb = b2[c];
            #pragma unroll
            for (int r = 0; r < 4; r++) {
                int n = nb + w16 + lgrp * 4 + r;
                if (n < N) O[(size_t)n * HID + c] = o[f][r] + bb;
            }
        }
    } else {
        const unsigned short* WT2 = type ? WfaT : WfpT;
        const float* bias2 = type ? bfa : bfp;
        kqv_tail_g(XbS, WT2, bias2, type, nb, N, w16, lrow, lgrp, even, Qh, KVb);
    }
}

extern "C" void kernel_launch(void* const* d_in, const int* in_sizes, int n_in,
                              void* d_out, int out_size, void* d_ws, size_t ws_size,
                              hipStream_t stream) {
    const float* x_paper  = (const float*)d_in[0];
    const float* x_author = (const float*)d_in[1];
    const int*   ei_ap    = (const int*)d_in[2];
    const int*   ei_pa    = (const int*)d_in[3];
    const int*   ei_pp    = (const int*)d_in[4];
    const float* W_in     = (const float*)d_in[5];
    const float* b_in     = (const float*)d_in[6];
    const float* W_kqv    = (const float*)d_in[7];
    const float* b_kqv    = (const float*)d_in[8];
    const float* W_krel   = (const float*)d_in[9];
    const float* W_vrel   = (const float*)d_in[10];
    const float* p_rel    = (const float*)d_in[11];
    const float* W_hout   = (const float*)d_in[12];
    const float* b_hout   = (const float*)d_in[13];
    const float* skip     = (const float*)d_in[14];
    const float* ln_g     = (const float*)d_in[15];
    const float* ln_b     = (const float*)d_in[16];
    const float* W_out    = (const float*)d_in[17];
    const float* b_out    = (const float*)d_in[18];
    float* out            = (float*)d_out;

    // ---- workspace layout ----
    char* ws = (char*)d_ws;
    unsigned short* Hb  = (unsigned short*)ws;                    // NTOT*64 bf16
    unsigned short* Qh  = Hb + (size_t)NTOT * HID;                // NTOT*64 f16 pairs
    unsigned* KVb       = (unsigned*)(Qh + (size_t)NTOT * HID);   // NSRC*64 dwords
    unsigned short* ABf = (unsigned short*)(KVb + (size_t)NSRC * HID); // NTOT*64 bf16
    unsigned short* WfpT = ABf + (size_t)NTOT * HID;    // 2 layers x JP*64 bf16
    float* bfp  = (float*)(WfpT + (size_t)2 * JP * 64); // 2 x JP
    unsigned short* WfaT = (unsigned short*)(bfp + 2 * JP); // 2 x JA*64
    float* bfa  = (float*)(WfaT + (size_t)2 * JA * 64); // 2 x JA
    unsigned short* WinT   = (unsigned short*)(bfa + 2 * JA);     // 2*64*128
    unsigned short* WhoutT = WinT + 2 * 64 * IN_DIM;              // L*2*64*64
    unsigned short* WoutT  = WhoutT + LAYERS * 2 * 64 * 64;       // 2*64*64
    int* cnt      = (int*)(WoutT + 2 * 64 * 64);
    int* row_ptr  = cnt + NTOT;
    int* cursor   = row_ptr + NTOT + 16;
    int* edge_src = cursor + NTOT;
    int* csum     = edge_src + ETOT;
    int* coff     = csum + 1024;

    dim3 blk(256);
    const int EB = (ETOT + 255) / 256;

    // ---- CSR build ----
    hipMemsetAsync(cnt, 0, NTOT * sizeof(int), stream);
    csr_count_kernel<<<EB, blk, 0, stream>>>(ei_ap, ei_pa, ei_pp, cnt);
    scan_chunk_sums<<<NCH, blk, 0, stream>>>(cnt, csum);
    scan_offsets<<<1, 1024, 0, stream>>>(csum, coff, NCH);
    scan_final<<<NCH, blk, 0, stream>>>(cnt, coff, row_ptr, cursor);
    csr_fill_kernel<<<EB, blk, 0, stream>>>(ei_ap, ei_pa, ei_pp, cursor, edge_src);

    // ---- weight prep (one-time per call) ----
    prep_weights<<<(2*64*IN_DIM + LAYERS*2*4096 + 2*4096 + 255) / 256, blk, 0, stream>>>(
        W_in, W_hout, W_out, WinT, WhoutT, WoutT);
    fuse_weights_all<<<(LAYERS * LSPAN + 255) / 256, blk, 0, stream>>>(
        W_kqv, b_kqv, W_krel, W_vrel, WfpT, bfp, WfaT, bfa);

    // ---- layer 0: input projection + kqv fused ----
    gemm_in_kqv<<<PT + AT, blk, 0, stream>>>(
        x_paper, x_author, WinT, b_in,
        WfpT, bfp, WfaT, bfa, Hb, Qh, KVb);
    attn_kernel<<<(NTOT + 3) / 4, blk, 0, stream>>>(
        Qh, KVb, p_rel, row_ptr, edge_src, ABf);
    // hout(0) + kqv(1) fused
    gemm_hout_fused<<<PT + AT, blk, 0, stream>>>(
        ABf, WhoutT, b_hout, skip, ln_g, ln_b, Hb,
        WfpT + (size_t)JP * 64, bfp + JP, WfaT + (size_t)JA * 64, bfa + JA,
        Qh, KVb, nullptr, nullptr, nullptr);
    attn_kernel<<<(NTOT + 3) / 4, blk, 0, stream>>>(
        Qh, KVb, p_rel + 3 * NH, row_ptr, edge_src, ABf);
    // hout(1) + W_out fused -> out
    gemm_hout_fused<<<PT + AT, blk, 0, stream>>>(
        ABf, WhoutT + (size_t)2 * 4096, b_hout + 2 * HID, skip + 2,
        ln_g + 2 * HID, ln_b + 2 * HID, Hb,
        nullptr, nullptr, nullptr, nullptr, Qh, KVb,
        WoutT, b_out, out);
}

// Round 21
// 341.215 us; speedup vs baseline: 1.2307x; 1.2307x over previous
//
#include <hip/hip_runtime.h>
#include <hip/hip_bf16.h>

// ---- problem constants (match reference) ----
#define NP 100000
#define NA 50000
#define NTOT 150000          // NP+NA
#define E0 300000
#define E1 300000
#define E2 200000
#define ETOT 800000
#define NH 4
#define HD 16
#define HID 64
#define IN_DIM 128
#define KQV 192
#define LAYERS 2
#define NSRC 250000          // NA + 2*NP
#define JP 320               // fused paper cols: q | k_et1 | k_et2 | v_et1 | v_et2
#define JA 192               // fused author cols: q | k_et0 | v_et0
#define NCH 586              // ceil(NTOT/256)
#define PT 1563              // ceil(NP/64)
#define AT 782               // ceil(NA/64)
#define LSPAN 33280          // per-layer fuse_weights idx span = 65*(JP+JA)

typedef __attribute__((ext_vector_type(8))) short bf16x8;   // 8 bf16 (4 VGPRs)
typedef __attribute__((ext_vector_type(4))) float f32x4;    // MFMA C/D
typedef _Float16 h16x2 __attribute__((ext_vector_type(2)));

__device__ __forceinline__ float gelu_exact(float x) {
    return 0.5f * x * (1.0f + erff(x * 0.7071067811865475f));
}
__device__ __forceinline__ unsigned short f2bf(float f) {
    unsigned u = __float_as_uint(f);
    return (unsigned short)((u + 0x7fffu + ((u >> 16) & 1u)) >> 16);
}
__device__ __forceinline__ float bf2f(unsigned short b) {
    return __uint_as_float((unsigned)b << 16);
}
__device__ __forceinline__ unsigned short f2h(float f) {
    union { _Float16 h; unsigned short u; } c;
    c.h = (_Float16)f;
    return c.u;
}

__device__ __forceinline__ void edge_decode(int e, const int* __restrict__ ei_ap,
                                            const int* __restrict__ ei_pa,
                                            const int* __restrict__ ei_pp,
                                            int& src, int& dst) {
    if (e < E0)            { src = ei_ap[e];                 dst = ei_ap[E0 + e]; }
    else if (e < E0 + E1)  { int le = e - E0;
                             src = NA + ei_pa[le];           dst = NP + ei_pa[E1 + le]; }
    else                   { int le = e - E0 - E1;
                             src = NA + NP + ei_pp[le];      dst = ei_pp[E2 + le]; }
}

// ---------------- CSR build ----------------
__global__ void csr_count_kernel(const int* __restrict__ ei_ap, const int* __restrict__ ei_pa,
                                 const int* __restrict__ ei_pp, int* __restrict__ cnt) {
    int e = blockIdx.x * 256 + threadIdx.x;
    if (e >= ETOT) return;
    int src, dst; edge_decode(e, ei_ap, ei_pa, ei_pp, src, dst);
    atomicAdd(&cnt[dst], 1);
}

__global__ void scan_chunk_sums(const int* __restrict__ cnt, int* __restrict__ csum) {
    __shared__ int sd[256];
    int c = blockIdx.x, t = threadIdx.x;
    int i = c * 256 + t;
    sd[t] = (i < NTOT) ? cnt[i] : 0;
    __syncthreads();
    for (int o = 128; o > 0; o >>= 1) { if (t < o) sd[t] += sd[t + o]; __syncthreads(); }
    if (t == 0) csum[c] = sd[0];
}

__global__ void scan_offsets(const int* __restrict__ csum, int* __restrict__ coff, int nch) {
    __shared__ int sd[1024];
    int t = threadIdx.x;
    int v = (t < nch) ? csum[t] : 0;
    sd[t] = v;
    __syncthreads();
    for (int o = 1; o < 1024; o <<= 1) {
        int x = (t >= o) ? sd[t - o] : 0;
        __syncthreads();
        sd[t] += x;
        __syncthreads();
    }
    if (t < nch) coff[t] = sd[t] - v;   // exclusive
}

__global__ void scan_final(const int* __restrict__ cnt, const int* __restrict__ coff,
                           int* __restrict__ row_ptr, int* __restrict__ cursor) {
    __shared__ int sd[256];
    int c = blockIdx.x, t = threadIdx.x, i = c * 256 + t;
    int v = (i < NTOT) ? cnt[i] : 0;
    sd[t] = v;
    __syncthreads();
    for (int o = 1; o < 256; o <<= 1) {
        int x = (t >= o) ? sd[t - o] : 0;
        __syncthreads();
        sd[t] += x;
        __syncthreads();
    }
    if (i < NTOT) { int ex = coff[c] + sd[t] - v; row_ptr[i] = ex; cursor[i] = ex; }
    if (i == 0) row_ptr[NTOT] = ETOT;
}

__global__ void csr_fill_kernel(const int* __restrict__ ei_ap, const int* __restrict__ ei_pa,
                                const int* __restrict__ ei_pp, int* __restrict__ cursor,
                                int* __restrict__ edge_src) {
    int e = blockIdx.x * 256 + threadIdx.x;
    if (e >= ETOT) return;
    int src, dst; edge_decode(e, ei_ap, ei_pa, ei_pp, src, dst);
    int pos = atomicAdd(&cursor[dst], 1);
    edge_src[pos] = src;
}

// ---------------- one-time weight prep: transposed bf16 panels ----------------
__global__ void prep_weights(const float* __restrict__ W_in, const float* __restrict__ W_hout,
                             const float* __restrict__ W_out,
                             unsigned short* __restrict__ WinT,
                             unsigned short* __restrict__ WhoutT,
                             unsigned short* __restrict__ WoutT) {
    int idx = blockIdx.x * 256 + threadIdx.x;
    if (idx < 2 * 64 * IN_DIM) {
        int t = idx >> 13, r = idx & 8191;
        int c = r >> 7, k = r & 127;
        WinT[idx] = f2bf(W_in[(size_t)t * IN_DIM * HID + (size_t)k * HID + c]);
        return;
    }
    int i2 = idx - 2 * 64 * IN_DIM;
    if (i2 < LAYERS * 2 * 4096) {
        int p = i2 >> 12, r = i2 & 4095;
        int c = r >> 6, k = r & 63;
        WhoutT[i2] = f2bf(W_hout[(size_t)p * 4096 + (size_t)k * HID + c]);
        return;
    }
    int i3 = i2 - LAYERS * 2 * 4096;
    if (i3 < 2 * 4096) {
        int p = i3 >> 12, r = i3 & 4095;
        int c = r >> 6, k = r & 63;
        WoutT[i3] = f2bf(W_out[(size_t)p * 4096 + (size_t)k * HID + c]);
    }
}

// ---------------- fused-weight build, BOTH layers in one launch ----------------
__global__ void fuse_weights_all(const float* __restrict__ Wkqv, const float* __restrict__ bkqv,
                                 const float* __restrict__ Wkrel, const float* __restrict__ Wvrel,
                                 unsigned short* __restrict__ WfpT, float* __restrict__ bfp,
                                 unsigned short* __restrict__ WfaT, float* __restrict__ bfa) {
    int gidx = blockIdx.x * 256 + threadIdx.x;
    if (gidx >= LAYERS * LSPAN) return;
    int lay = gidx / LSPAN;
    int idx = gidx - lay * LSPAN;
    const float* Wkqv_l = Wkqv + (size_t)lay * 2 * HID * KQV;
    const float* bkqv_l = bkqv + (size_t)lay * 2 * KQV;
    const float* Wkrel_l = Wkrel + (size_t)lay * 3 * NH * HD * HD;
    const float* Wvrel_l = Wvrel + (size_t)lay * 3 * NH * HD * HD;
    unsigned short* WfpT_l = WfpT + (size_t)lay * JP * 64;
    unsigned short* WfaT_l = WfaT + (size_t)lay * JA * 64;
    float* bfp_l = bfp + (size_t)lay * JP;
    float* bfa_l = bfa + (size_t)lay * JA;

    int type, i, j;
    if (idx < 65 * JP) { type = 0; i = idx / JP; j = idx % JP; }
    else {
        int r = idx - 65 * JP;
        type = 1; i = r / JA; j = r % JA;
    }
    int c = j >> 6, jj = j & 63, h = jj >> 4, e = jj & 15;
    const float* Wk = Wkqv_l + (size_t)type * HID * KQV;
    const float* bk = bkqv_l + type * KQV;
    float val;
    if (c == 0) {
        val = (i < 64) ? Wk[i * KQV + 64 + jj] : bk[64 + jj];
    } else {
        int et, isV;
        if (type == 0) { et = (c == 1 || c == 3) ? 1 : 2; isV = (c >= 3); }
        else           { et = 0; isV = (c == 2); }
        const float* Wr = (isV ? Wvrel_l : Wkrel_l) + (size_t)(et * NH + h) * HD * HD;
        int sb = (isV ? 128 : 0) + h * HD;
        val = 0.0f;
        #pragma unroll
        for (int d = 0; d < HD; d++) {
            float a = (i < 64) ? Wk[i * KQV + sb + d] : bk[sb + d];
            val += a * Wr[d * HD + e];
        }
    }
    if (i < 64) (type ? WfaT_l : WfpT_l)[(size_t)j * 64 + i] = f2bf(val);
    else        (type ? bfa_l : bfp_l)[j] = val;
}

// ---------------- shared device helpers (2x2 layout, used by in_kqv / kqv_sep) ----------------
__device__ __forceinline__ void mfma64(const unsigned short* A, const unsigned short* W,
                                       int wr, int wc, int lrow, int lgrp,
                                       f32x4& a00, f32x4& a01, f32x4& a10, f32x4& a11) {
    a00 = (f32x4){0.f,0.f,0.f,0.f}; a01 = a00; a10 = a00; a11 = a00;
    #pragma unroll
    for (int ks = 0; ks < 2; ks++) {
        int ko = ks * 32 + lgrp * 8;
        bf16x8 x0 = *(const bf16x8*)&A[(wr + lrow) * 72 + ko];
        bf16x8 x1 = *(const bf16x8*)&A[(wr + 16 + lrow) * 72 + ko];
        bf16x8 w0 = *(const bf16x8*)&W[(wc + lrow) * 72 + ko];
        bf16x8 w1 = *(const bf16x8*)&W[(wc + 16 + lrow) * 72 + ko];
        a00 = __builtin_amdgcn_mfma_f32_16x16x32_bf16(x0, w0, a00, 0, 0, 0);
        a01 = __builtin_amdgcn_mfma_f32_16x16x32_bf16(x0, w1, a01, 0, 0, 0);
        a10 = __builtin_amdgcn_mfma_f32_16x16x32_bf16(x1, w0, a10, 0, 0, 0);
        a11 = __builtin_amdgcn_mfma_f32_16x16x32_bf16(x1, w1, a11, 0, 0, 0);
    }
}

__device__ __forceinline__ void store_q(f32x4 a00, f32x4 a01, f32x4 a10, f32x4 a11,
                                        float bq0, float bq1, int c0, int c1, bool even,
                                        int nb, int N, int wr, int lgrp,
                                        unsigned short* Qbase) {
    #pragma unroll
    for (int mi = 0; mi < 2; mi++) {
        const f32x4 a0 = mi ? a10 : a00;
        const f32x4 a1 = mi ? a11 : a01;
        int rbase = wr + mi * 16 + lgrp * 4;
        #pragma unroll
        for (int r = 0; r < 4; r++) {
            int n = nb + rbase + r;
            unsigned own = (unsigned)f2h(a0[r] + bq0) | ((unsigned)f2h(a1[r] + bq1) << 16);
            unsigned oth = __shfl_xor(own, 1, 64);
            if (even && n < N) {
                unsigned* qp = (unsigned*)(Qbase + (size_t)n * HID);
                qp[c0 >> 1] = (own & 0xffffu) | (oth << 16);
                qp[c1 >> 1] = (own >> 16) | (oth & 0xffff0000u);
            }
        }
    }
}

__device__ __forceinline__ void store_kv(f32x4 k00, f32x4 k01, f32x4 k10, f32x4 k11,
                                         f32x4 v00, f32x4 v01, f32x4 v10, f32x4 v11,
                                         float bk0, float bk1, float bv0, float bv1,
                                         int c0, int c1, bool even,
                                         int nb, int N, int wr, int lgrp,
                                         int noff, unsigned* KVb) {
    #pragma unroll
    for (int mi = 0; mi < 2; mi++) {
        const f32x4 ak0 = mi ? k10 : k00;
        const f32x4 ak1 = mi ? k11 : k01;
        const f32x4 av0 = mi ? v10 : v00;
        const f32x4 av1 = mi ? v11 : v01;
        int rbase = wr + mi * 16 + lgrp * 4;
        #pragma unroll
        for (int r = 0; r < 4; r++) {
            int n = nb + rbase + r;
            unsigned own0 = (unsigned)f2h(ak0[r] + bk0) | ((unsigned)f2h(av0[r] + bv0) << 16);
            unsigned oth0 = __shfl_xor(own0, 1, 64);
            unsigned own1 = (unsigned)f2h(ak1[r] + bk1) | ((unsigned)f2h(av1[r] + bv1) << 16);
            unsigned oth1 = __shfl_xor(own1, 1, 64);
            if (n < N) {
                unsigned* dst = KVb + (((size_t)(noff + n)) << 6);
                unsigned w0 = even ? ((own0 & 0xffffu) | (oth0 << 16))
                                   : ((oth0 >> 16) | (own0 & 0xffff0000u));
                unsigned w1 = even ? ((own1 & 0xffffu) | (oth1 << 16))
                                   : ((oth1 >> 16) | (own1 & 0xffff0000u));
                dst[c0] = w0;
                dst[c1] = w1;
            }
        }
    }
}

// kqv phase over LDS-resident h tile HS (72-stride), panels staged into PA/PB.
__device__ __forceinline__ void kqv_phase(const unsigned short* HS,
                                          unsigned short* PA, unsigned short* PB,
                                          const unsigned short* WT, const float* bias2,
                                          int type, int tid, int nb, int N,
                                          int wr, int wc, int lrow, int lgrp,
                                          int c0, int c1, bool even,
                                          unsigned short* Qh, unsigned* KVb) {
    #pragma unroll
    for (int it = 0; it < 4; it++) {
        int idx = it * 256 + tid;
        int c = idx >> 4, kg = (idx & 15) * 4;
        *(ushort4*)&PA[c * 72 + kg] = *(const ushort4*)(WT + (size_t)c * 64 + kg);
    }
    __syncthreads();
    {
        f32x4 q00, q01, q10, q11;
        mfma64(HS, PA, wr, wc, lrow, lgrp, q00, q01, q10, q11);
        store_q(q00, q01, q10, q11, bias2[c0], bias2[c1], c0, c1, even,
                nb, N, wr, lgrp, Qh + (size_t)(type ? NP : 0) * HID);
    }
    __syncthreads();
    int ng = type ? 1 : 2;
    for (int g = 0; g < ng; g++) {
        int kc = type ? 64 : (g ? 128 : 64);
        int vc = type ? 128 : (g ? 256 : 192);
        int nf = type ? 0 : (g ? NA + NP : NA);
        #pragma unroll
        for (int it = 0; it < 4; it++) {
            int idx = it * 256 + tid;
            int c = idx >> 4, kg = (idx & 15) * 4;
            *(ushort4*)&PA[c * 72 + kg] = *(const ushort4*)(WT + (size_t)(kc + c) * 64 + kg);
            *(ushort4*)&PB[c * 72 + kg] = *(const ushort4*)(WT + (size_t)(vc + c) * 64 + kg);
        }
        __syncthreads();
        f32x4 k00, k01, k10, k11, v00, v01, v10, v11;
        mfma64(HS, PA, wr, wc, lrow, lgrp, k00, k01, k10, k11);
        mfma64(HS, PB, wr, wc, lrow, lgrp, v00, v01, v10, v11);
        store_kv(k00, k01, k10, k11, v00, v01, v10, v11,
                 bias2[kc + c0], bias2[kc + c1], bias2[vc + c0], bias2[vc + c1],
                 c0, c1, even, nb, N, wr, lgrp, nf, KVb);
        __syncthreads();
    }
}

// ---------------- r16-strip MFMA from LDS panel (hout_r16) ----------------
__device__ __forceinline__ void mfma_r16(const unsigned short* X, const unsigned short* P,
                                         int w16, int lrow, int lgrp, f32x4* acc) {
    #pragma unroll
    for (int f = 0; f < 4; f++) acc[f] = (f32x4){0.f, 0.f, 0.f, 0.f};
    #pragma unroll
    for (int ks = 0; ks < 2; ks++) {
        int ko = ks * 32 + lgrp * 8;
        bf16x8 a = *(const bf16x8*)&X[(w16 + lrow) * 72 + ko];
        #pragma unroll
        for (int f = 0; f < 4; f++) {
            bf16x8 bb = *(const bf16x8*)&P[(f * 16 + lrow) * 72 + ko];
            acc[f] = __builtin_amdgcn_mfma_f32_16x16x32_bf16(a, bb, acc[f], 0, 0, 0);
        }
    }
}

#define STAGE_PANEL(dst, src)                                                   \
    { _Pragma("unroll")                                                         \
      for (int it_ = 0; it_ < 4; it_++) {                                       \
          int idx_ = it_ * 256 + tid;                                           \
          int c_ = idx_ >> 4, kg_ = (idx_ & 15) * 4;                            \
          *(ushort4*)&dst[c_ * 72 + kg_] =                                      \
              *(const ushort4*)((src) + (size_t)c_ * 64 + kg_);                 \
      } }

// ---------------- gemm_in fused with layer-0 kqv (R19-known-good) ----------------
__global__ __launch_bounds__(256) void gemm_in_kqv(
    const float* __restrict__ xp, const float* __restrict__ xa,
    const unsigned short* __restrict__ WinT, const float* __restrict__ b_in,
    const unsigned short* __restrict__ WfpT, const float* __restrict__ bfp,
    const unsigned short* __restrict__ WfaT, const float* __restrict__ bfa,
    unsigned short* __restrict__ Hb, unsigned short* __restrict__ Qh,
    unsigned* __restrict__ KVb)
{
    __shared__ unsigned short smem[17408];   // 34816 B overlay
    unsigned short* XB  = smem;              // phase A: [64][136]
    unsigned short* WTl = smem + 8704;       // phase A: [64][136]
    unsigned short* HS  = smem;              // phase B: [64][72]
    unsigned short* PA  = smem + 4608;       // panel A  [64][72]
    unsigned short* PB  = smem + 9216;       // panel B  [64][72]

    int b = blockIdx.x, tid = threadIdx.x;
    int type = (b >= PT);
    int tile = type ? (b - PT) : b;
    int N = type ? NA : NP;
    const float* X = type ? xa : xp;
    const unsigned short* WT = WinT + (size_t)type * 64 * IN_DIM;
    const float* bias = b_in + type * HID;
    unsigned short* H = Hb + (type ? (size_t)NP * HID : 0);
    int nb = tile * 64;

    {
        int row = tid >> 2, cg = (tid & 3) * 32;
        int n = nb + row;
        if (n < N) {
            const float* xr = X + (size_t)n * IN_DIM + cg;
            #pragma unroll
            for (int i = 0; i < 32; i += 4) {
                float4 v = *(const float4*)(xr + i);
                *(ushort4*)&XB[row * 136 + cg + i] =
                    make_ushort4(f2bf(v.x), f2bf(v.y), f2bf(v.z), f2bf(v.w));
            }
        } else {
            #pragma unroll
            for (int i = 0; i < 32; i += 4)
                *(ushort4*)&XB[row * 136 + cg + i] = make_ushort4(0, 0, 0, 0);
        }
    }
    #pragma unroll
    for (int it = 0; it < 8; it++) {
        int idx = it * 256 + tid;
        int c = idx >> 5, kg = (idx & 31) * 4;
        *(ushort4*)&WTl[c * 136 + kg] = *(const ushort4*)(WT + (size_t)c * IN_DIM + kg);
    }
    __syncthreads();

    int w = tid >> 6, lane = tid & 63;
    int wr = (w >> 1) * 32, wc = (w & 1) * 32;
    int lrow = lane & 15, lgrp = lane >> 4;
    int c0 = wc + lrow, c1 = wc + 16 + lrow;
    bool even = ((lrow & 1) == 0);

    f32x4 acc00 = {0.f,0.f,0.f,0.f}, acc01 = {0.f,0.f,0.f,0.f};
    f32x4 acc10 = {0.f,0.f,0.f,0.f}, acc11 = {0.f,0.f,0.f,0.f};
    #pragma unroll
    for (int ks = 0; ks < 4; ks++) {
        int ko = ks * 32 + lgrp * 8;
        bf16x8 a0 = *(const bf16x8*)&XB[(wr + lrow) * 136 + ko];
        bf16x8 a1 = *(const bf16x8*)&XB[(wr + 16 + lrow) * 136 + ko];
        bf16x8 b0 = *(const bf16x8*)&WTl[(wc + lrow) * 136 + ko];
        bf16x8 b1 = *(const bf16x8*)&WTl[(wc + 16 + lrow) * 136 + ko];
        acc00 = __builtin_amdgcn_mfma_f32_16x16x32_bf16(a0, b0, acc00, 0, 0, 0);
        acc01 = __builtin_amdgcn_mfma_f32_16x16x32_bf16(a0, b1, acc01, 0, 0, 0);
        acc10 = __builtin_amdgcn_mfma_f32_16x16x32_bf16(a1, b0, acc10, 0, 0, 0);
        acc11 = __builtin_amdgcn_mfma_f32_16x16x32_bf16(a1, b1, acc11, 0, 0, 0);
    }
    __syncthreads();   // all MFMA reads of XB/WTl done; smem reusable

    float bias0 = bias[c0], bias1 = bias[c1];
    #pragma unroll
    for (int mi = 0; mi < 2; mi++) {
        const f32x4 accn0 = mi ? acc10 : acc00;
        const f32x4 accn1 = mi ? acc11 : acc01;
        int rbase = wr + mi * 16 + lgrp * 4;
        #pragma unroll
        for (int r = 0; r < 4; r++) {
            int n = nb + rbase + r;
            unsigned short h0 = f2bf(accn0[r] + bias0);
            unsigned short h1 = f2bf(accn1[r] + bias1);
            HS[(rbase + r) * 72 + c0] = h0;
            HS[(rbase + r) * 72 + c1] = h1;
            unsigned own = (unsigned)h0 | ((unsigned)h1 << 16);
            unsigned oth = __shfl_xor(own, 1, 64);
            if (even && n < N) {
                unsigned* hp = (unsigned*)(H + (size_t)n * HID);
                hp[c0 >> 1] = (own & 0xffffu) | (oth << 16);
                hp[c1 >> 1] = (own >> 16) | (oth & 0xffff0000u);
            }
        }
    }
    __syncthreads();

    const unsigned short* WT2 = type ? WfaT : WfpT;
    const float* bias2 = type ? bfa : bfp;
    kqv_phase(HS, PA, PB, WT2, bias2, type, tid, nb, N,
              wr, wc, lrow, lgrp, c0, c1, even, Qh, KVb);
}

// ---------------- fused attention (unchanged) ----------------
__global__ __launch_bounds__(256) void attn_kernel(
    const unsigned short* __restrict__ Qh, const unsigned* __restrict__ KVb,
    const float* __restrict__ p_rel, const int* __restrict__ row_ptr,
    const int* __restrict__ edge_src, unsigned short* __restrict__ ABf)
{
    int wid = threadIdx.x >> 6, lane = threadIdx.x & 63;
    int n = blockIdx.x * 4 + wid;
    if (n >= NTOT) return;
    int half = lane >> 5;
    int p = lane & 31;
    int h = p >> 3;
    unsigned qw = *(const unsigned*)(Qh + (((size_t)n) << 6) + 2 * p);
    union { unsigned u; h16x2 v; _Float16 f[2]; } qc; qc.u = qw;
    h16x2 qh = qc.v;
    const float INV_LN2 = 1.4426950408889634f;
    float pr0 = p_rel[h] * 0.25f * INV_LN2;
    float pr1 = p_rel[4 + h] * 0.25f * INV_LN2;
    float pr2 = p_rel[8 + h] * 0.25f * INV_LN2;
    int beg = row_ptr[n], end = row_ptr[n + 1];
    float s = 0.0f, acc0 = 0.f, acc1 = 0.f;
    for (int e = beg; e < end; e += 4) {
        int e0 = e + half;
        int e1 = e + 2 + half;
        bool v0 = (e0 < end), v1 = (e1 < end);
        int s0 = v0 ? edge_src[e0] : 0;
        int s1 = v1 ? edge_src[e1] : 0;
        uint2 kv0 = *(const uint2*)(KVb + (((size_t)s0) << 6) + 2 * p);
        uint2 kv1 = *(const uint2*)(KVb + (((size_t)s1) << 6) + 2 * p);
        float d0, d1;
#if __has_builtin(__builtin_amdgcn_fdot2)
        {
            union { unsigned u; h16x2 v; } ck;
            ck.u = kv0.x; d0 = __builtin_amdgcn_fdot2(qh, ck.v, 0.0f, false);
            ck.u = kv1.x; d1 = __builtin_amdgcn_fdot2(qh, ck.v, 0.0f, false);
        }
#else
        {
            union { unsigned u; _Float16 f[2]; } ck;
            float q0 = (float)qc.f[0], q1 = (float)qc.f[1];
            ck.u = kv0.x; d0 = q0 * (float)ck.f[0] + q1 * (float)ck.f[1];
            ck.u = kv1.x; d1 = q0 * (float)ck.f[0] + q1 * (float)ck.f[1];
        }
#endif
        d0 += __shfl_xor(d0, 1, 64);  d1 += __shfl_xor(d1, 1, 64);
        d0 += __shfl_xor(d0, 2, 64);  d1 += __shfl_xor(d1, 2, 64);
        d0 += __shfl_xor(d0, 4, 64);  d1 += __shfl_xor(d1, 4, 64);
        float pa = (s0 < NA) ? pr0 : ((s0 < NA + NP) ? pr1 : pr2);
        float pb = (s1 < NA) ? pr0 : ((s1 < NA + NP) ? pr1 : pr2);
        float a0 = v0 ? fminf(d0 * pa, 80.0f) : -INFINITY;
        float a1 = v1 ? fminf(d1 * pb, 80.0f) : -INFINITY;
        float p0 = exp2f(a0);
        float p1 = exp2f(a1);
        s += p0 + p1;
        union { unsigned u; _Float16 f[2]; } cv0, cv1;
        cv0.u = kv0.y; cv1.u = kv1.y;
        acc0 += p0 * (float)cv0.f[0] + p1 * (float)cv1.f[0];
        acc1 += p0 * (float)cv0.f[1] + p1 * (float)cv1.f[1];
    }
    s    += __shfl_xor(s, 32, 64);
    acc0 += __shfl_xor(acc0, 32, 64);
    acc1 += __shfl_xor(acc1, 32, 64);
    if (half == 0) {
        float inv = 1.0f / (s + 1e-16f);
        unsigned pack = (unsigned)f2bf(acc0 * inv) | ((unsigned)f2bf(acc1 * inv) << 16);
        *(unsigned*)(ABf + (((size_t)n) << 6) + 2 * p) = pack;
    }
}

// ---------------- hout only (r16 strips, LDS panel): blend+LN+gelu in regs ----------------
// Non-final: 1 barrier; writes Hb. Final: +2 barriers, fused W_out -> out.
__global__ __launch_bounds__(256) void gemm_hout_r16(
    const unsigned short* __restrict__ ABf, const unsigned short* __restrict__ WhT,
    const float* __restrict__ bhout, const float* __restrict__ skip_p,
    const float* __restrict__ lng, const float* __restrict__ lnb,
    unsigned short* __restrict__ Hb,
    const unsigned short* __restrict__ WoT, const float* __restrict__ bout,
    float* __restrict__ outp)
{
    __shared__ unsigned short XbS[64 * 72];   // 9216 B
    __shared__ unsigned short PA[64 * 72];    // 9216 B

    int b = blockIdx.x, tid = threadIdx.x;
    int type = (b >= PT);
    int tile = type ? (b - PT) : b;
    int N = type ? NA : NP;
    size_t base_off = type ? (size_t)NP * HID : 0;
    const unsigned short* X = ABf + base_off;
    const unsigned short* W = WhT + (size_t)type * 4096;
    const float* bias = bhout + type * HID;
    unsigned short* H = Hb + base_off;
    int nb = tile * 64;
    bool fin = (WoT != nullptr);

    int w = tid >> 6, lane = tid & 63;
    int w16 = w * 16, lrow = lane & 15, lgrp = lane >> 4;
    bool even = ((lrow & 1) == 0);

    // stage own 16 rows: XbS = gelu(attn_out) bf16; cooperative panel stage
    {
        int row = w16 + (lane >> 2), cg = (lane & 3) * 16;
        int n = nb + row;
        unsigned short tmp[16];
        if (n < N) {
            const unsigned short* xr = X + (((size_t)n) << 6) + cg;
            #pragma unroll
            for (int i = 0; i < 16; i += 4) {
                ushort4 v = *(const ushort4*)(xr + i);
                tmp[i]   = f2bf(gelu_exact(bf2f(v.x)));
                tmp[i+1] = f2bf(gelu_exact(bf2f(v.y)));
                tmp[i+2] = f2bf(gelu_exact(bf2f(v.z)));
                tmp[i+3] = f2bf(gelu_exact(bf2f(v.w)));
            }
        } else {
            #pragma unroll
            for (int i = 0; i < 16; i++) tmp[i] = 0;
        }
        #pragma unroll
        for (int i = 0; i < 16; i += 4)
            *(ushort4*)&XbS[row * 72 + cg + i] =
                make_ushort4(tmp[i], tmp[i+1], tmp[i+2], tmp[i+3]);
    }
    STAGE_PANEL(PA, W)
    __syncthreads();

    f32x4 acc[4];
    mfma_r16(XbS, PA, w16, lrow, lgrp, acc);

    // blend + LN + gelu in registers
    float a = 1.0f / (1.0f + __expf(-skip_p[type]));
    float oma = 1.0f - a;
    float lnv[4][4];
    {
        float bh[4], gg[4], ll[4];
        #pragma unroll
        for (int f = 0; f < 4; f++) {
            int c = f * 16 + lrow;
            bh[f] = bias[c];
            gg[f] = lng[type * HID + c];
            ll[f] = lnb[type * HID + c];
        }
        #pragma unroll
        for (int r = 0; r < 4; r++) {
            int n = nb + w16 + lgrp * 4 + r;
            float x0, x1, x2, x3;
            if (n < N) {
                const unsigned short* hp = H + (size_t)n * HID;
                x0 = a * (acc[0][r] + bh[0]) + oma * bf2f(hp[0 * 16 + lrow]);
                x1 = a * (acc[1][r] + bh[1]) + oma * bf2f(hp[1 * 16 + lrow]);
                x2 = a * (acc[2][r] + bh[2]) + oma * bf2f(hp[2 * 16 + lrow]);
                x3 = a * (acc[3][r] + bh[3]) + oma * bf2f(hp[3 * 16 + lrow]);
            } else { x0 = x1 = x2 = x3 = 0.f; }
            float sum = x0 + x1 + x2 + x3;
            sum += __shfl_xor(sum, 1, 64); sum += __shfl_xor(sum, 2, 64);
            sum += __shfl_xor(sum, 4, 64); sum += __shfl_xor(sum, 8, 64);
            float mean = sum * (1.0f / 64.0f);
            float d0 = x0 - mean, d1 = x1 - mean, d2 = x2 - mean, d3 = x3 - mean;
            float sq = d0*d0 + d1*d1 + d2*d2 + d3*d3;
            sq += __shfl_xor(sq, 1, 64); sq += __shfl_xor(sq, 2, 64);
            sq += __shfl_xor(sq, 4, 64); sq += __shfl_xor(sq, 8, 64);
            float rstd = rsqrtf(sq * (1.0f / 64.0f) + 1e-5f);
            lnv[r][0] = gelu_exact(d0 * rstd * gg[0] + ll[0]);
            lnv[r][1] = gelu_exact(d1 * rstd * gg[1] + ll[1]);
            lnv[r][2] = gelu_exact(d2 * rstd * gg[2] + ll[2]);
            lnv[r][3] = gelu_exact(d3 * rstd * gg[3] + ll[3]);
            if (!fin) {
                #pragma unroll
                for (int fp = 0; fp < 4; fp += 2) {
                    int c0 = fp * 16 + lrow, c1 = c0 + 16;
                    unsigned own = (unsigned)f2bf(lnv[r][fp]) | ((unsigned)f2bf(lnv[r][fp + 1]) << 16);
                    unsigned oth = __shfl_xor(own, 1, 64);
                    if (even && n < N) {
                        unsigned* hp2 = (unsigned*)(H + (size_t)n * HID);
                        hp2[c0 >> 1] = (own & 0xffffu) | (oth << 16);
                        hp2[c1 >> 1] = (own >> 16) | (oth & 0xffff0000u);
                    }
                }
            }
        }
    }
    if (!fin) return;

    // final: restage XbS <- bf16(lnv) (own rows), PA <- W_out panel
    __syncthreads();   // all waves done reading XbS/PA
    #pragma unroll
    for (int r = 0; r < 4; r++) {
        int row = w16 + lgrp * 4 + r;
        #pragma unroll
        for (int f = 0; f < 4; f++)
            XbS[row * 72 + f * 16 + lrow] = f2bf(lnv[r][f]);
    }
    STAGE_PANEL(PA, WoT + (size_t)type * 4096)
    __syncthreads();

    f32x4 o[4];
    mfma_r16(XbS, PA, w16, lrow, lgrp, o);
    const float* b2 = bout + type * HID;
    float* O = outp + base_off;
    #pragma unroll
    for (int f = 0; f < 4; f++) {
        int c = f * 16 + lrow;
        float bb = b2[c];
        #pragma unroll
        for (int r = 0; r < 4; r++) {
            int n = nb + w16 + lgrp * 4 + r;
            if (n < N) O[(size_t)n * HID + c] = o[f][r] + bb;
        }
    }
}

// ---------------- standalone kqv (reads Hb), for layer 1 ----------------
__global__ __launch_bounds__(256) void gemm_kqv_sep(
    const unsigned short* __restrict__ Hb,
    const unsigned short* __restrict__ WfpT, const float* __restrict__ bfp,
    const unsigned short* __restrict__ WfaT, const float* __restrict__ bfa,
    unsigned short* __restrict__ Qh, unsigned* __restrict__ KVb)
{
    __shared__ unsigned short HS[64 * 72];
    __shared__ unsigned short PA[64 * 72];
    __shared__ unsigned short PB[64 * 72];

    int b = blockIdx.x, tid = threadIdx.x;
    int type = (b >= PT);
    int tile = type ? (b - PT) : b;
    int N = type ? NA : NP;
    const unsigned short* X = Hb + (type ? (size_t)NP * HID : 0);
    int nb = tile * 64;

    {
        int row = tid >> 2, cg = (tid & 3) * 16;
        int n = nb + row;
        if (n < N) {
            const unsigned short* xr = X + (size_t)n * HID + cg;
            *(ushort4*)&HS[row * 72 + cg]      = *(const ushort4*)(xr);
            *(ushort4*)&HS[row * 72 + cg + 4]  = *(const ushort4*)(xr + 4);
            *(ushort4*)&HS[row * 72 + cg + 8]  = *(const ushort4*)(xr + 8);
            *(ushort4*)&HS[row * 72 + cg + 12] = *(const ushort4*)(xr + 12);
        } else {
            #pragma unroll
            for (int i = 0; i < 16; i += 4)
                *(ushort4*)&HS[row * 72 + cg + i] = make_ushort4(0, 0, 0, 0);
        }
    }
    __syncthreads();

    int w = tid >> 6, lane = tid & 63;
    int wr = (w >> 1) * 32, wc = (w & 1) * 32;
    int lrow = lane & 15, lgrp = lane >> 4;
    int c0 = wc + lrow, c1 = wc + 16 + lrow;
    bool even = ((lrow & 1) == 0);

    const unsigned short* WT2 = type ? WfaT : WfpT;
    const float* bias2 = type ? bfa : bfp;
    kqv_phase(HS, PA, PB, WT2, bias2, type, tid, nb, N,
              wr, wc, lrow, lgrp, c0, c1, even, Qh, KVb);
}

extern "C" void kernel_launch(void* const* d_in, const int* in_sizes, int n_in,
                              void* d_out, int out_size, void* d_ws, size_t ws_size,
                              hipStream_t stream) {
    const float* x_paper  = (const float*)d_in[0];
    const float* x_author = (const float*)d_in[1];
    const int*   ei_ap    = (const int*)d_in[2];
    const int*   ei_pa    = (const int*)d_in[3];
    const int*   ei_pp    = (const int*)d_in[4];
    const float* W_in     = (const float*)d_in[5];
    const float* b_in     = (const float*)d_in[6];
    const float* W_kqv    = (const float*)d_in[7];
    const float* b_kqv    = (const float*)d_in[8];
    const float* W_krel   = (const float*)d_in[9];
    const float* W_vrel   = (const float*)d_in[10];
    const float* p_rel    = (const float*)d_in[11];
    const float* W_hout   = (const float*)d_in[12];
    const float* b_hout   = (const float*)d_in[13];
    const float* skip     = (const float*)d_in[14];
    const float* ln_g     = (const float*)d_in[15];
    const float* ln_b     = (const float*)d_in[16];
    const float* W_out    = (const float*)d_in[17];
    const float* b_out    = (const float*)d_in[18];
    float* out            = (float*)d_out;

    // ---- workspace layout ----
    char* ws = (char*)d_ws;
    unsigned short* Hb  = (unsigned short*)ws;                    // NTOT*64 bf16
    unsigned short* Qh  = Hb + (size_t)NTOT * HID;                // NTOT*64 f16 pairs
    unsigned* KVb       = (unsigned*)(Qh + (size_t)NTOT * HID);   // NSRC*64 dwords
    unsigned short* ABf = (unsigned short*)(KVb + (size_t)NSRC * HID); // NTOT*64 bf16
    unsigned short* WfpT = ABf + (size_t)NTOT * HID;    // 2 layers x JP*64 bf16
    float* bfp  = (float*)(WfpT + (size_t)2 * JP * 64); // 2 x JP
    unsigned short* WfaT = (unsigned short*)(bfp + 2 * JP); // 2 x JA*64
    float* bfa  = (float*)(WfaT + (size_t)2 * JA * 64); // 2 x JA
    unsigned short* WinT   = (unsigned short*)(bfa + 2 * JA);     // 2*64*128
    unsigned short* WhoutT = WinT + 2 * 64 * IN_DIM;              // L*2*64*64
    unsigned short* WoutT  = WhoutT + LAYERS * 2 * 64 * 64;       // 2*64*64
    int* cnt      = (int*)(WoutT + 2 * 64 * 64);
    int* row_ptr  = cnt + NTOT;
    int* cursor   = row_ptr + NTOT + 16;
    int* edge_src = cursor + NTOT;
    int* csum     = edge_src + ETOT;
    int* coff     = csum + 1024;

    dim3 blk(256);
    const int EB = (ETOT + 255) / 256;

    // ---- CSR build ----
    hipMemsetAsync(cnt, 0, NTOT * sizeof(int), stream);
    csr_count_kernel<<<EB, blk, 0, stream>>>(ei_ap, ei_pa, ei_pp, cnt);
    scan_chunk_sums<<<NCH, blk, 0, stream>>>(cnt, csum);
    scan_offsets<<<1, 1024, 0, stream>>>(csum, coff, NCH);
    scan_final<<<NCH, blk, 0, stream>>>(cnt, coff, row_ptr, cursor);
    csr_fill_kernel<<<EB, blk, 0, stream>>>(ei_ap, ei_pa, ei_pp, cursor, edge_src);

    // ---- weight prep (one-time per call) ----
    prep_weights<<<(2*64*IN_DIM + LAYERS*2*4096 + 2*4096 + 255) / 256, blk, 0, stream>>>(
        W_in, W_hout, W_out, WinT, WhoutT, WoutT);
    fuse_weights_all<<<(LAYERS * LSPAN + 255) / 256, blk, 0, stream>>>(
        W_kqv, b_kqv, W_krel, W_vrel, WfpT, bfp, WfaT, bfa);

    // ---- layer 0: input projection + kqv fused ----
    gemm_in_kqv<<<PT + AT, blk, 0, stream>>>(
        x_paper, x_author, WinT, b_in,
        WfpT, bfp, WfaT, bfa, Hb, Qh, KVb);
    attn_kernel<<<(NTOT + 3) / 4, blk, 0, stream>>>(
        Qh, KVb, p_rel, row_ptr, edge_src, ABf);
    // hout(0): blend+LN+gelu -> Hb
    gemm_hout_r16<<<PT + AT, blk, 0, stream>>>(
        ABf, WhoutT, b_hout, skip, ln_g, ln_b, Hb,
        nullptr, nullptr, nullptr);
    // kqv(1): Hb -> Qh/KVb
    gemm_kqv_sep<<<PT + AT, blk, 0, stream>>>(
        Hb, WfpT + (size_t)JP * 64, bfp + JP, WfaT + (size_t)JA * 64, bfa + JA,
        Qh, KVb);
    attn_kernel<<<(NTOT + 3) / 4, blk, 0, stream>>>(
        Qh, KVb, p_rel + 3 * NH, row_ptr, edge_src, ABf);
    // hout(1) + W_out fused -> out
    gemm_hout_r16<<<PT + AT, blk, 0, stream>>>(
        ABf, WhoutT + (size_t)2 * 4096, b_hout + 2 * HID, skip + 2,
        ln_g + 2 * HID, ln_b + 2 * HID, Hb,
        WoutT, b_out, out);
}